// Round 1
// baseline (431.914 us; speedup 1.0000x reference)
//
#include <hip/hip_runtime.h>
#include <math.h>

// cummax along axis 1 of [B=16, T=512, H=64, C=128] fp32.
// Flat index: ((b*T + t)*H + h)*C + c -> T-stride = H*C = 8192 floats.
//
// Segmented scan, block-local (single pass, minimal 512 MiB traffic):
//   T=512 split into SEG=16 segments of TSEG=32.
//   Thread = (float2-column, segment). Phase 1: 32 pure loads into registers
//   (32 loads in flight, no stores sharing vmcnt). Local cummax in regs.
//   Segment maxes -> LDS -> one barrier -> exclusive prefix -> Phase 2:
//   32 pure stores of max(prefix, local_cummax).
//
// Occupancy: 2048 blocks x 512 thr = 1,048,576 threads (16x the old kernel's
// 65,536). __launch_bounds__(512,4) caps VGPR at 128 -> 2 blocks/CU resident
// = 16 waves/CU, each with 16 KiB of loads in flight during phase 1.

#define T_DIM 512
#define HC    8192        // H*C floats per (b,t) slab
#define HC2   4096        // float2 per (b,t) slab
#define B_DIM 16
#define SEG   16          // segments along T
#define TSEG  32          // T_DIM / SEG
#define COLS  32          // float2-columns per block
#define NCOL2 65536       // B * HC2 total float2 columns

__global__ __launch_bounds__(512, 4) void cummax_seg(const float* __restrict__ in,
                                                     float* __restrict__ out) {
    __shared__ float2 segmax[SEG][COLS];

    const int tid = threadIdx.x;
    const int c   = tid & (COLS - 1);   // column within block
    const int s   = tid >> 5;           // segment index, uniform per half-wave

    const int col = blockIdx.x * COLS + c;   // global float2 column
    const int b   = col >> 12;               // / HC2
    const int cp  = col & (HC2 - 1);

    const float2* __restrict__ src =
        (const float2*)(in + (size_t)b * T_DIM * HC) + (size_t)(s * TSEG) * HC2 + cp;
    float2* __restrict__ dst =
        (float2*)(out + (size_t)b * T_DIM * HC) + (size_t)(s * TSEG) * HC2 + cp;

    // ---- Phase 1: pure load burst (32 independent global_load_dwordx2) ----
    float2 v[TSEG];
    #pragma unroll
    for (int i = 0; i < TSEG; ++i) {
        v[i] = src[(size_t)i * HC2];
    }

    // ---- Local running cummax in registers (indices all compile-time) ----
    float mx = -INFINITY, my = -INFINITY;
    #pragma unroll
    for (int i = 0; i < TSEG; ++i) {
        mx = fmaxf(mx, v[i].x);
        my = fmaxf(my, v[i].y);
        v[i].x = mx;
        v[i].y = my;
    }

    // ---- Publish segment max, one barrier, exclusive prefix over segments ----
    segmax[s][c] = make_float2(mx, my);
    __syncthreads();

    float px = -INFINITY, py = -INFINITY;
    for (int j = 0; j < s; ++j) {
        float2 sm = segmax[j][c];
        px = fmaxf(px, sm.x);
        py = fmaxf(py, sm.y);
    }

    // ---- Phase 2: pure store burst ----
    #pragma unroll
    for (int i = 0; i < TSEG; ++i) {
        float2 o;
        o.x = fmaxf(px, v[i].x);
        o.y = fmaxf(py, v[i].y);
        dst[(size_t)i * HC2] = o;
    }
}

extern "C" void kernel_launch(void* const* d_in, const int* in_sizes, int n_in,
                              void* d_out, int out_size, void* d_ws, size_t ws_size,
                              hipStream_t stream) {
    const float* in = (const float*)d_in[0];
    float* out = (float*)d_out;

    // 2048 blocks x 512 threads = one thread per (float2-column, segment).
    dim3 grid(NCOL2 / COLS);
    dim3 block(COLS * SEG);
    cummax_seg<<<grid, block, 0, stream>>>(in, out);
}

// Round 2
// 419.907 us; speedup vs baseline: 1.0286x; 1.0286x over previous
//
#include <hip/hip_runtime.h>
#include <hip/hip_bf16.h>
#include <math.h>

// cummax along axis 1 of [B=16, T=512, H=64, C=128] fp32.
// Flat index: ((b*T + t)*H + h)*C + c -> T-stride = H*C = 8192 floats.
// One thread per float2 column-pair; sequential running max over T.
//
// Memory-bound: 512 MiB minimal traffic -> 85.3 us floor at the 6.29 TB/s
// achievable ceiling (m13 float4-copy). Counter analysis (rounds 0-1) shows
// this kernel's dispatch runs ~85 us (absent from top-5 table whose cutoff
// is 164 us; JSON dur_us additionally contains ~332 us of 2x 1-GiB harness
// poison fills at ~166 us each). I.e. this structure is AT the HBM roofline.
//
// Round-1 experiment (register-tile segmented scan, 16x threads, pure
// load/store phases) regressed the kernel-attributable time 85 -> ~100 us
// (VGPR pressure + barrier), confirming the limiter is NOT latency/occupancy.
// Reverted to this measured-best structure.

#define T_DIM 512
#define HC 8192           // H*C floats per (b,t) slab
#define B_DIM 16

__global__ __launch_bounds__(128) void cummax_kernel(const float* __restrict__ in,
                                                     float* __restrict__ out) {
    // gid in [0, B*HC/2) = [0, 65536)
    int gid = blockIdx.x * blockDim.x + threadIdx.x;
    int b   = gid >> 12;          // / (HC/2 = 4096)
    int cp  = gid & 4095;         // float2-column within the batch slab

    const float2* __restrict__ src =
        (const float2*)(in  + (size_t)b * T_DIM * HC) + cp;
    float2* __restrict__ dst =
        (float2*)(out + (size_t)b * T_DIM * HC) + cp;

    float mx = -INFINITY;
    float my = -INFINITY;

    #pragma unroll 8
    for (int t = 0; t < T_DIM; ++t) {
        float2 v = src[t * (HC / 2)];
        mx = fmaxf(mx, v.x);
        my = fmaxf(my, v.y);
        float2 o;
        o.x = mx;
        o.y = my;
        dst[t * (HC / 2)] = o;
    }
}

extern "C" void kernel_launch(void* const* d_in, const int* in_sizes, int n_in,
                              void* d_out, int out_size, void* d_ws, size_t ws_size,
                              hipStream_t stream) {
    const float* in = (const float*)d_in[0];
    float* out = (float*)d_out;

    // 65536 threads total: 512 blocks x 128 threads -> 2 blocks/CU across 256 CUs.
    dim3 grid(512);
    dim3 block(128);
    cummax_kernel<<<grid, block, 0, stream>>>(in, out);
}